// Round 1
// baseline (57896.637 us; speedup 1.0000x reference)
//
#include <hip/hip_runtime.h>
#include <stdint.h>

#define NN 4096      // nodes / steps
#define DD 256       // hidden dim
#define NWG 64       // workgroups
#define TT 256       // threads per WG
#define ROWS 64      // NN/NWG rows per WG
#define GR 16        // gate rows per WG (1024/NWG)
#define NSTEPS 4096

// ---------------- workspace layout (bytes) ----------------
#define OFF_CNT      0u          // unsigned barrier counter (padded line)
#define OFF_SCAL     256u        // [0]=maxHpNorm bits, [1]=ebBound bits
#define OFF_QBUF     512u        // 2*256 f32 (double-buffered q)
#define OFF_PS       2560u       // 64 f32 partial softmax sums
#define OFF_PR       3072u       // 64*256 f32 partial r-tilde
#define OFF_EB       68608u      // 4096 f32  (h @ b_a)
#define OFF_BPACK    84992u      // 1024 f32 packed bias
#define OFF_WPACK    89088u      // 1024*512 f32 packed gate weights
#define OFF_HB       2186240u    // 4096*256 bf16 (h)
#define OFF_HPB      4283392u    // 4096*256 bf16 packed [wg][k4][row] (Hp)
// total ~6.09 MB

#define SMEM_BYTES 69632

__device__ __forceinline__ float bf2f(unsigned short u) {
  return __uint_as_float(((unsigned)u) << 16);
}
__device__ __forceinline__ unsigned short f2bf(float f) {
  unsigned x = __float_as_uint(f);
  unsigned r = x + 0x7fffu + ((x >> 16) & 1u);
  return (unsigned short)(r >> 16);
}

// ---------------- K0: init dynamic state ----------------
__global__ void k0_init(char* ws) {
  int t = threadIdx.x;
  unsigned* u = (unsigned*)ws;
  float* f = (float*)ws;
  if (t == 0) {
    u[OFF_CNT / 4] = 0u;
    u[OFF_SCAL / 4] = 0u;
    u[OFF_SCAL / 4 + 1] = 0u;
  }
  for (int i = t; i < 512; i += TT) f[OFF_QBUF / 4 + i] = 0.f;
  for (int i = t; i < 64; i += TT) f[OFF_PS / 4 + i] = 1.0f / NWG;
  for (int i = t; i < 64 * 256; i += TT) f[OFF_PR / 4 + i] = 0.f;
}

// ---------------- K1: Hp = h @ W_a (bf16, packed), eb = h @ b_a, bounds ----------------
__global__ __launch_bounds__(256) void k1_hp(const float* __restrict__ h,
                                             const float* __restrict__ W_a,
                                             const float* __restrict__ b_a,
                                             char* ws) {
  __shared__ float hL1[16][256];
  __shared__ float scr[16][256];
  __shared__ float redN[4][16];
  __shared__ float redE[4][16];
  const int t = threadIdx.x, b = blockIdx.x;
  const int i0 = b * 16;
  for (int i = t; i < 16 * 256; i += 256) hL1[i >> 8][i & 255] = h[i0 * 256 + i];
  __syncthreads();
  float acc[16];
#pragma unroll
  for (int ii = 0; ii < 16; ++ii) acc[ii] = 0.f;
  for (int j = 0; j < 256; ++j) {
    float wa = W_a[j * 256 + t];
#pragma unroll
    for (int ii = 0; ii < 16; ++ii) acc[ii] += hL1[ii][j] * wa;
  }
#pragma unroll
  for (int ii = 0; ii < 16; ++ii) scr[ii][t] = acc[ii];
  const int lane = t & 63, wv = t >> 6;
  const float ba = b_a[t];
  for (int ii = 0; ii < 16; ++ii) {
    float a2 = acc[ii] * acc[ii];
    float eb = hL1[ii][t] * ba;
    for (int m = 32; m; m >>= 1) { a2 += __shfl_xor(a2, m); eb += __shfl_xor(eb, m); }
    if (lane == 0) { redN[wv][ii] = a2; redE[wv][ii] = eb; }
  }
  __syncthreads();
  unsigned* scal = (unsigned*)(ws + OFF_SCAL);
  float* ebg = (float*)(ws + OFF_EB);
  if (t < 16) {
    float n2 = redN[0][t] + redN[1][t] + redN[2][t] + redN[3][t];
    float ebv = redE[0][t] + redE[1][t] + redE[2][t] + redE[3][t];
    ebg[i0 + t] = ebv;
    atomicMax(scal + 0, __float_as_uint(sqrtf(n2)));
    atomicMax(scal + 1, __float_as_uint(fabsf(ebv)));
  }
  // pack Hp slice: [wg][k4][row_local], 4 bf16 per uint2 along k
  uint2* hpB = (uint2*)(ws + OFF_HPB);
  const int wq = b >> 2, sub = b & 3;
  for (int idx = t; idx < 16 * 64; idx += 256) {
    int ii = idx >> 6, k4 = idx & 63;
    unsigned short u0 = f2bf(scr[ii][4 * k4 + 0]);
    unsigned short u1 = f2bf(scr[ii][4 * k4 + 1]);
    unsigned short u2 = f2bf(scr[ii][4 * k4 + 2]);
    unsigned short u3 = f2bf(scr[ii][4 * k4 + 3]);
    uint2 pv;
    pv.x = (unsigned)u0 | ((unsigned)u1 << 16);
    pv.y = (unsigned)u2 | ((unsigned)u3 << 16);
    int rl = sub * 16 + ii;
    hpB[wq * 4096 + k4 * 64 + rl] = pv;
  }
}

// ---------------- K2: pack h (bf16), fold gate weights/bias ----------------
__global__ void k2_pack(const float* __restrict__ h, const float* __restrict__ W_ih,
                        const float* __restrict__ W_hh, const float* __restrict__ b_ih,
                        const float* __restrict__ b_hh, char* ws) {
  unsigned short* hB = (unsigned short*)(ws + OFF_HB);
  float* wpack = (float*)(ws + OFF_WPACK);
  float* bpack = (float*)(ws + OFF_BPACK);
  int idx0 = blockIdx.x * blockDim.x + threadIdx.x;
  int stride = gridDim.x * blockDim.x;
  for (int i = idx0; i < NN * DD; i += stride) hB[i] = f2bf(h[i]);
  for (int i = idx0; i < 1024 * 512; i += stride) {
    int row = i >> 9, c = i & 511;
    int g = row >> 8, d = row & 255;
    int wq = d >> 2, dl = d & 3;
    float v = W_ih[row * 512 + c];
    if (c < 256) v += W_hh[row * 256 + c];
    wpack[(wq * GR + g * 4 + dl) * 512 + c] = v;
  }
  for (int i = idx0; i < 1024; i += stride) {
    int g = i >> 8, d = i & 255, wq = d >> 2, dl = d & 3;
    bpack[wq * GR + g * 4 + dl] = b_ih[i] + b_hh[i];
  }
}

// ---------------- grid barrier (co-resident WGs, monotonic counter) ----------------
__device__ __forceinline__ void gbar(unsigned* cnt, unsigned target) {
  __syncthreads();
  if (threadIdx.x == 0) {
    __hip_atomic_fetch_add(cnt, 1u, __ATOMIC_RELEASE, __HIP_MEMORY_SCOPE_AGENT);
    unsigned guard = 0;
    while (__hip_atomic_load(cnt, __ATOMIC_ACQUIRE, __HIP_MEMORY_SCOPE_AGENT) < target) {
      __builtin_amdgcn_s_sleep(1);
      if (++guard > (1u << 23)) break;  // safety: garbage instead of hang
    }
  }
  __syncthreads();
}

// ---------------- main persistent kernel ----------------
__global__ __launch_bounds__(TT, 1) void s2s_main(char* __restrict__ ws,
                                                  float* __restrict__ out) {
  extern __shared__ char smem[];
  uint2* HpL = (uint2*)smem;                              // 32768 B
  unsigned short* hL = (unsigned short*)(smem + 32768);   // 32768 B
  float* qrL = (float*)(smem + 65536);                    // 512 f32
  float* pL = (float*)(smem + 67584);                     // 64
  float* gL = (float*)(smem + 67840);                     // 16
  float* cLs = (float*)(smem + 67904);                    // 4
  float* red4 = (float*)(smem + 67920);                   // 4
  float* ebL = (float*)(smem + 67936);                    // 64

  const int w = blockIdx.x, tid = threadIdx.x;
  unsigned* cnt = (unsigned*)(ws + OFF_CNT);
  const unsigned* scal = (const unsigned*)(ws + OFF_SCAL);
  float* qbuf = (float*)(ws + OFF_QBUF);
  float* ps = (float*)(ws + OFF_PS);
  float* pr = (float*)(ws + OFF_PR);
  const float* ebg = (const float*)(ws + OFF_EB);
  const float* bpack = (const float*)(ws + OFF_BPACK);
  const float* wpack = (const float*)(ws + OFF_WPACK);
  const uint2* hpB = (const uint2*)(ws + OFF_HPB);
  const uint2* hBv = (const uint2*)(ws + OFF_HB) + (size_t)w * (ROWS * DD / 4);

  for (int i = tid; i < 4096; i += TT) HpL[i] = hpB[w * 4096 + i];
  for (int i = tid; i < 4096; i += TT) ((uint2*)hL)[i] = hBv[i];
  if (tid < 64) ebL[tid] = ebg[w * 64 + tid];
  if (tid < 4) cLs[tid] = 0.f;
  const float maxHpN = __uint_as_float(scal[0]);
  const float ebB = __uint_as_float(scal[1]);
  __syncthreads();

  unsigned syncs = 0;
  const int gr_lr = tid >> 4, gr_li = tid & 15;
  const float* wrow = wpack + (size_t)(w * GR + gr_lr) * 512;
  const float brow = bpack[w * GR + gr_lr];
  const int wv4 = tid >> 6, l = tid & 63, rl = l & 15, li2 = l >> 4;
  const int rr = wv4 * 16 + rl;

  for (int t = 0; t < NSTEPS; ++t) {
    const int cur = t & 1, nxt = cur ^ 1;
    // ---- phase A: combine r, gates, LSTM -> q_{t+1} ----
    float sacc = 0.f, racc = 0.f;
#pragma unroll 8
    for (int v = 0; v < NWG; ++v) {
      sacc += ps[v];
      racc += pr[v * 256 + tid];
    }
    sacc = fmaxf(sacc, 1e-35f);
    qrL[256 + tid] = racc / sacc;   // r_t
    qrL[tid] = qbuf[cur * 256 + tid];  // q_t
    __syncthreads();
    float acc = 0.f;
#pragma unroll
    for (int j = 0; j < 8; ++j) {
      int c0 = gr_li * 4 + j * 64;
      const float4 wv = *(const float4*)(wrow + c0);
      const float4 qv = *(const float4*)(qrL + c0);
      acc += wv.x * qv.x + wv.y * qv.y + wv.z * qv.z + wv.w * qv.w;
    }
    acc += __shfl_xor(acc, 8);
    acc += __shfl_xor(acc, 4);
    acc += __shfl_xor(acc, 2);
    acc += __shfl_xor(acc, 1);
    if (gr_li == 0) gL[gr_lr] = acc + brow;
    __syncthreads();
    if (tid < 4) {
      float gi = gL[tid], gf = gL[4 + tid], gg = gL[8 + tid], go = gL[12 + tid];
      float co = cLs[tid];
      float si = 1.f / (1.f + __expf(-gi));
      float sf = 1.f / (1.f + __expf(-gf));
      float so = 1.f / (1.f + __expf(-go));
      float cn = sf * co + si * tanhf(gg);
      cLs[tid] = cn;
      qbuf[nxt * 256 + (w << 2) + tid] = so * tanhf(cn);
    }
    gbar(cnt, NWG * (++syncs));
    // ---- phase B: e = Hp.q + eb, p = exp(e - Mhat), partials ----
    float qv = qbuf[nxt * 256 + tid];
    qrL[tid] = qv;
    float nr = qv * qv;
#pragma unroll
    for (int m = 32; m; m >>= 1) nr += __shfl_xor(nr, m);
    if (l == 0) red4[wv4] = nr;
    __syncthreads();
    const float qnorm = sqrtf(red4[0] + red4[1] + red4[2] + red4[3]);
    const float Mhat = 0.5f * maxHpN * qnorm + ebB;
    float eacc = 0.f;
#pragma unroll
    for (int j = 0; j < 16; ++j) {
      const int k4 = li2 * 16 + j;
      const uint2 hp = HpL[(k4 << 6) + rr];
      const float* qp = qrL + (k4 << 2);
      eacc += bf2f((unsigned short)(hp.x)) * qp[0] +
              bf2f((unsigned short)(hp.x >> 16)) * qp[1] +
              bf2f((unsigned short)(hp.y)) * qp[2] +
              bf2f((unsigned short)(hp.y >> 16)) * qp[3];
    }
    eacc += __shfl_xor(eacc, 16);
    eacc += __shfl_xor(eacc, 32);
    if (li2 == 0) {
      float e = eacc + ebL[rr];
      pL[rr] = __expf(fminf(e - Mhat, 74.f));
    }
    __syncthreads();
    if (tid < 64) {
      float sv = pL[tid];
#pragma unroll
      for (int m = 32; m; m >>= 1) sv += __shfl_xor(sv, m);
      if (tid == 0) ps[w] = sv;
    }
    float r2 = 0.f;
#pragma unroll 8
    for (int r3 = 0; r3 < 64; ++r3) r2 += pL[r3] * bf2f(hL[(r3 << 8) + tid]);
    pr[(w << 8) + tid] = r2;
    gbar(cnt, NWG * (++syncs));
  }
  // ---- epilogue: q_star = [q_final, r_final] ----
  if (w == 0) {
    float sacc = 0.f, racc = 0.f;
    for (int v = 0; v < NWG; ++v) {
      sacc += ps[v];
      racc += pr[v * 256 + tid];
    }
    sacc = fmaxf(sacc, 1e-35f);
    out[tid] = qbuf[0 * 256 + tid];  // parity: q_{4096} lives in buffer 0
    out[256 + tid] = racc / sacc;
  }
}

extern "C" void kernel_launch(void* const* d_in, const int* in_sizes, int n_in,
                              void* d_out, int out_size, void* d_ws, size_t ws_size,
                              hipStream_t stream) {
  const float* h = (const float*)d_in[0];
  const float* W_ih = (const float*)d_in[1];
  const float* W_hh = (const float*)d_in[2];
  const float* b_ih = (const float*)d_in[3];
  const float* b_hh = (const float*)d_in[4];
  const float* W_a = (const float*)d_in[5];
  const float* b_a = (const float*)d_in[6];
  char* ws = (char*)d_ws;
  float* out = (float*)d_out;

  // allow 68KB dynamic LDS (idempotent; ignore error)
  (void)hipFuncSetAttribute(reinterpret_cast<const void*>(s2s_main),
                            hipFuncAttributeMaxDynamicSharedMemorySize, SMEM_BYTES);

  k0_init<<<1, TT, 0, stream>>>(ws);
  k1_hp<<<256, 256, 0, stream>>>(h, W_a, b_a, ws);
  k2_pack<<<1024, 256, 0, stream>>>(h, W_ih, W_hh, b_ih, b_hh, ws);
  s2s_main<<<NWG, TT, SMEM_BYTES, stream>>>(ws, out);
}

// Round 3
// 52095.770 us; speedup vs baseline: 1.1114x; 1.1114x over previous
//
#include <hip/hip_runtime.h>
#include <stdint.h>

#define NN 4096      // nodes / steps
#define DD 256       // hidden dim
#define NWG 64       // workgroups
#define TT 256       // threads per WG
#define ROWS 64      // NN/NWG rows per WG
#define GR 16        // gate rows per WG (1024/NWG)
#define NSTEPS 4096

// ---------------- workspace layout (bytes) ----------------
#define OFF_FLAGP    0u          // 64 flags, 128B stride
#define OFF_FLAGQ    8192u       // 64 flags, 128B stride
#define OFF_SCAL     16384u      // [0]=maxHpNorm bits, [1]=ebBound bits
#define OFF_QBUF     16640u      // 2*256 f32 (double-buffered q)
#define OFF_PS       18688u      // 64 f32 partial softmax sums
#define OFF_PR       18944u      // 64*256 f32 partial r-tilde
#define OFF_EB       84480u      // 4096 f32  (h @ b_a)
#define OFF_BPACK    100864u     // 1024 f32 packed bias
#define OFF_WPACK    104960u     // 1024*512 f32 packed gate weights -> +2097152
#define OFF_HPB      2202112u    // 4096*256 bf16 packed [wg][k4][row] (Hp) -> +2097152
#define OFF_HP2      4299264u    // paired-row h bf16: [wg][r2:32][col:256] uint -> +2097152
// total 6,396,416 B (~6.1 MB)

// ---------------- LDS layout ----------------
#define S_HPL    0u        // 32768  uint2 [k4:64][row:64]
#define S_HP     32768u    // 32768  uint  [r2:32][col:256]
#define S_WL     65536u    // 32768  f32   [16][512]
#define S_QRL    98304u    // 2048   f32   [512] : q | r
#define S_PRL    100352u   // 4096   f32   [4][256]
#define S_EL     104448u   // 1024   f32   [4][64]
#define S_PL     105472u   // 256    f32   [64]
#define S_GL     105728u   // 64     f32   [16]
#define S_CLS    105792u   // 16     f32   [4]
#define S_RED4   105808u   // 16
#define S_SL     105824u   // 16
#define S_EBL    105840u   // 256    f32   [64]
#define S_DEAD   106096u   // 4
#define SMEM_BYTES 106496

__device__ __forceinline__ float bf2f(unsigned short u) {
  return __uint_as_float(((unsigned)u) << 16);
}
__device__ __forceinline__ unsigned short f2bf(float f) {
  unsigned x = __float_as_uint(f);
  unsigned r = x + 0x7fffu + ((x >> 16) & 1u);
  return (unsigned short)(r >> 16);
}

// ---------------- K0: init dynamic state ----------------
__global__ void k0_init(char* ws) {
  int t = threadIdx.x;
  unsigned* u = (unsigned*)ws;
  float* f = (float*)ws;
  for (int i = t; i < 4096; i += TT) u[i] = 0u;  // flagP + flagQ regions
  if (t == 0) { u[OFF_SCAL / 4] = 0u; u[OFF_SCAL / 4 + 1] = 0u; }
  for (int i = t; i < 512; i += TT) f[OFF_QBUF / 4 + i] = 0.f;
  for (int i = t; i < 64; i += TT) f[OFF_PS / 4 + i] = 1.0f / NWG;
  for (int i = t; i < 64 * 256; i += TT) f[OFF_PR / 4 + i] = 0.f;
}

// ---------------- K1: Hp = h @ W_a (bf16, packed), eb = h @ b_a, bounds ----------------
__global__ __launch_bounds__(256) void k1_hp(const float* __restrict__ h,
                                             const float* __restrict__ W_a,
                                             const float* __restrict__ b_a,
                                             char* ws) {
  __shared__ float hL1[16][256];
  __shared__ float scr[16][256];
  __shared__ float redN[4][16];
  __shared__ float redE[4][16];
  const int t = threadIdx.x, b = blockIdx.x;
  const int i0 = b * 16;
  for (int i = t; i < 16 * 256; i += 256) hL1[i >> 8][i & 255] = h[i0 * 256 + i];
  __syncthreads();
  float acc[16];
#pragma unroll
  for (int ii = 0; ii < 16; ++ii) acc[ii] = 0.f;
  for (int j = 0; j < 256; ++j) {
    float wa = W_a[j * 256 + t];
#pragma unroll
    for (int ii = 0; ii < 16; ++ii) acc[ii] += hL1[ii][j] * wa;
  }
#pragma unroll
  for (int ii = 0; ii < 16; ++ii) scr[ii][t] = acc[ii];
  const int lane = t & 63, wv = t >> 6;
  const float ba = b_a[t];
  for (int ii = 0; ii < 16; ++ii) {
    float a2 = acc[ii] * acc[ii];
    float eb = hL1[ii][t] * ba;
    for (int m = 32; m; m >>= 1) { a2 += __shfl_xor(a2, m); eb += __shfl_xor(eb, m); }
    if (lane == 0) { redN[wv][ii] = a2; redE[wv][ii] = eb; }
  }
  __syncthreads();
  unsigned* scal = (unsigned*)(ws + OFF_SCAL);
  float* ebg = (float*)(ws + OFF_EB);
  if (t < 16) {
    float n2 = redN[0][t] + redN[1][t] + redN[2][t] + redN[3][t];
    float ebv = redE[0][t] + redE[1][t] + redE[2][t] + redE[3][t];
    ebg[i0 + t] = ebv;
    atomicMax(scal + 0, __float_as_uint(sqrtf(n2)));
    atomicMax(scal + 1, __float_as_uint(fabsf(ebv)));
  }
  // pack Hp slice: [wg][k4][row_local], 4 bf16 per uint2 along k
  uint2* hpB = (uint2*)(ws + OFF_HPB);
  const int wq = b >> 2, sub = b & 3;
  for (int idx = t; idx < 16 * 64; idx += 256) {
    int ii = idx >> 6, k4 = idx & 63;
    unsigned short u0 = f2bf(scr[ii][4 * k4 + 0]);
    unsigned short u1 = f2bf(scr[ii][4 * k4 + 1]);
    unsigned short u2 = f2bf(scr[ii][4 * k4 + 2]);
    unsigned short u3 = f2bf(scr[ii][4 * k4 + 3]);
    uint2 pv;
    pv.x = (unsigned)u0 | ((unsigned)u1 << 16);
    pv.y = (unsigned)u2 | ((unsigned)u3 << 16);
    int rl = sub * 16 + ii;
    hpB[wq * 4096 + k4 * 64 + rl] = pv;
  }
}

// ---------------- K2: pack paired h (bf16), fold gate weights/bias ----------------
__global__ void k2_pack(const float* __restrict__ h, const float* __restrict__ W_ih,
                        const float* __restrict__ W_hh, const float* __restrict__ b_ih,
                        const float* __restrict__ b_hh, char* ws) {
  unsigned* hp2 = (unsigned*)(ws + OFF_HP2);
  float* wpack = (float*)(ws + OFF_WPACK);
  float* bpack = (float*)(ws + OFF_BPACK);
  int idx0 = blockIdx.x * blockDim.x + threadIdx.x;
  int stride = gridDim.x * blockDim.x;
  // paired rows: hp2[w*8192 + r2*256 + col] = pack(h[w*64+2r2][col], h[w*64+2r2+1][col])
  for (int i = idx0; i < NN * DD / 2; i += stride) {
    int col = i & 255;
    int r2 = (i >> 8) & 31;
    int w = i >> 13;
    int row0 = (w * 64 + 2 * r2) * 256 + col;
    hp2[i] = (unsigned)f2bf(h[row0]) | ((unsigned)f2bf(h[row0 + 256]) << 16);
  }
  for (int i = idx0; i < 1024 * 512; i += stride) {
    int row = i >> 9, c = i & 511;
    int g = row >> 8, d = row & 255;
    int wq = d >> 2, dl = d & 3;
    float v = W_ih[row * 512 + c];
    if (c < 256) v += W_hh[row * 256 + c];
    wpack[(wq * GR + g * 4 + dl) * 512 + c] = v;
  }
  for (int i = idx0; i < 1024; i += stride) {
    int g = i >> 8, d = i & 255, wq = d >> 2, dl = d & 3;
    bpack[wq * GR + g * 4 + dl] = b_ih[i] + b_hh[i];
  }
}

// ---------------- flag wait: 64 threads poll 64 per-WG flags ----------------
__device__ __forceinline__ void wait_flags(const unsigned* flags, unsigned need,
                                           int tid, int* dead) {
  if (!*dead) {
    if (tid < NWG) {
      const unsigned* p = flags + tid * 32;
      unsigned guard = 0;
      while (__hip_atomic_load(p, __ATOMIC_RELAXED, __HIP_MEMORY_SCOPE_AGENT) < need) {
        if (++guard > (1u << 24)) { *dead = 1; break; }  // no hang; garbage result
      }
    }
  }
  __syncthreads();
  __builtin_amdgcn_fence(__ATOMIC_ACQUIRE, "agent");
}

// ---------------- main persistent kernel ----------------
__global__ __launch_bounds__(TT, 1) void s2s_main(char* __restrict__ ws,
                                                  float* __restrict__ out) {
  extern __shared__ char smem[];
  uint2* HpL = (uint2*)(smem + S_HPL);
  unsigned* hP = (unsigned*)(smem + S_HP);
  float* wL = (float*)(smem + S_WL);
  float* qrL = (float*)(smem + S_QRL);
  float* prL = (float*)(smem + S_PRL);
  float* eL = (float*)(smem + S_EL);
  float* pL = (float*)(smem + S_PL);
  float* gL = (float*)(smem + S_GL);
  float* cLs = (float*)(smem + S_CLS);
  float* red4 = (float*)(smem + S_RED4);
  float* sL = (float*)(smem + S_SL);
  float* ebL = (float*)(smem + S_EBL);
  int* dead = (int*)(smem + S_DEAD);

  const int w = blockIdx.x, tid = threadIdx.x;
  unsigned* flagP = (unsigned*)(ws + OFF_FLAGP);
  unsigned* flagQ = (unsigned*)(ws + OFF_FLAGQ);
  const unsigned* scal = (const unsigned*)(ws + OFF_SCAL);
  float* qbuf = (float*)(ws + OFF_QBUF);
  float* ps = (float*)(ws + OFF_PS);
  float* pr = (float*)(ws + OFF_PR);
  const float* ebg = (const float*)(ws + OFF_EB);
  const float* bpack = (const float*)(ws + OFF_BPACK);
  const float* wpack = (const float*)(ws + OFF_WPACK);
  const uint2* hpB = (const uint2*)(ws + OFF_HPB) + (size_t)w * 4096;
  const unsigned* hp2 = (const unsigned*)(ws + OFF_HP2) + (size_t)w * 8192;

  for (int i = tid; i < 4096; i += TT) HpL[i] = hpB[i];
  for (int i = tid; i < 8192; i += TT) hP[i] = hp2[i];
  for (int i = tid; i < 8192; i += TT) wL[i] = wpack[(size_t)w * 8192 + i];
  if (tid < 64) ebL[tid] = ebg[w * 64 + tid];
  if (tid < 4) cLs[tid] = 0.f;
  if (tid == 0) *dead = 0;
  qrL[tid] = 0.f;
  qrL[256 + tid] = 0.f;
  const float maxHpN = __uint_as_float(scal[0]);
  const float ebB = __uint_as_float(scal[1]);
  __syncthreads();

  const int gr_lr = tid >> 4, gr_li = tid & 15;
  const float* wrow = wL + gr_lr * 512;
  const float brow = bpack[w * GR + gr_lr];
  const int wv4 = tid >> 6, l = tid & 63;

  for (int t = 0; t < NSTEPS; ++t) {
    // ==== phase A: q_t = LSTM(q_{t-1}, r_{t-1}) ====
    // overlap: Wq @ q_{t-1} before waiting (q_{t-1} already in qrL[0:256])
    float acc = 0.f;
#pragma unroll
    for (int j = 0; j < 4; ++j) {
      int c0 = gr_li * 4 + j * 64;
      const float4 wv = *(const float4*)(wrow + c0);
      const float4 qv = *(const float4*)(qrL + c0);
      acc += wv.x * qv.x + wv.y * qv.y + wv.z * qv.z + wv.w * qv.w;
    }
    wait_flags(flagP, (unsigned)t, tid, dead);
    // combine partials: wave wv4 sums slices [wv4*16, wv4*16+16), lane l -> 4 cols
    {
      const float* prv = pr + (wv4 * 16) * 256 + (l << 2);
      float rx = 0.f, ry = 0.f, rz = 0.f, rw = 0.f;
#pragma unroll
      for (int i = 0; i < 16; ++i) {
        const float4 v = *(const float4*)(prv + i * 256);
        rx += v.x; ry += v.y; rz += v.z; rw += v.w;
      }
      float* d = prL + wv4 * 256 + (l << 2);
      d[0] = rx; d[1] = ry; d[2] = rz; d[3] = rw;
      if (wv4 == 0) {
        float s = ps[l];
#pragma unroll
        for (int m = 32; m; m >>= 1) s += __shfl_xor(s, m);
        if (l == 0) sL[0] = fmaxf(s, 1e-35f);
      }
    }
    __syncthreads();
    {
      float rsum = prL[tid] + prL[256 + tid] + prL[512 + tid] + prL[768 + tid];
      qrL[256 + tid] = rsum / sL[0];  // r_{t-1}
    }
    __syncthreads();
    // Wr @ r
#pragma unroll
    for (int j = 4; j < 8; ++j) {
      int c0 = gr_li * 4 + j * 64;
      const float4 wv = *(const float4*)(wrow + c0);
      const float4 qv = *(const float4*)(qrL + c0);
      acc += wv.x * qv.x + wv.y * qv.y + wv.z * qv.z + wv.w * qv.w;
    }
    acc += __shfl_xor(acc, 8);
    acc += __shfl_xor(acc, 4);
    acc += __shfl_xor(acc, 2);
    acc += __shfl_xor(acc, 1);
    if (gr_li == 0) gL[gr_lr] = acc + brow;
    __syncthreads();
    if (tid < 4) {
      float gi = gL[tid], gf = gL[4 + tid], gg = gL[8 + tid], go = gL[12 + tid];
      float co = cLs[tid];
      float si = 1.f / (1.f + __expf(-gi));
      float sf = 1.f / (1.f + __expf(-gf));
      float so = 1.f / (1.f + __expf(-go));
      float cn = sf * co + si * tanhf(gg);
      cLs[tid] = cn;
      qbuf[(t & 1) * 256 + (w << 2) + tid] = so * tanhf(cn);
    }
    if (tid == 0)  // same wave as q writers: release waits the wave's stores
      __hip_atomic_store(flagQ + w * 32, (unsigned)(t + 1), __ATOMIC_RELEASE,
                         __HIP_MEMORY_SCOPE_AGENT);

    // ==== phase B: e = Hp q + eb, partials ====
    wait_flags(flagQ, (unsigned)(t + 1), tid, dead);
    float qv = qbuf[(t & 1) * 256 + tid];
    qrL[tid] = qv;  // keep q_t local for next phase A
    float nr = qv * qv;
#pragma unroll
    for (int m = 32; m; m >>= 1) nr += __shfl_xor(nr, m);
    if (l == 0) red4[wv4] = nr;
    __syncthreads();
    const float qnorm = sqrtf(red4[0] + red4[1] + red4[2] + red4[3]);
    const float Mhat = 0.5f * maxHpN * qnorm + ebB;
    // e partial: wave wv4 covers k4 in [wv4*16,+16), lane l = row
    float eacc = 0.f;
#pragma unroll
    for (int j = 0; j < 16; ++j) {
      const int k4 = wv4 * 16 + j;
      const uint2 hp = HpL[(k4 << 6) + l];
      const float* qp = qrL + (k4 << 2);
      eacc += bf2f((unsigned short)(hp.x)) * qp[0] +
              bf2f((unsigned short)(hp.x >> 16)) * qp[1] +
              bf2f((unsigned short)(hp.y)) * qp[2] +
              bf2f((unsigned short)(hp.y >> 16)) * qp[3];
    }
    eL[(wv4 << 6) + l] = eacc;
    __syncthreads();
    if (tid < 64) {
      float e = eL[tid] + eL[64 + tid] + eL[128 + tid] + eL[192 + tid] + ebL[tid];
      float p = __expf(fminf(e - Mhat, 60.f));
      pL[tid] = p;
      float sv = p;
#pragma unroll
      for (int m = 32; m; m >>= 1) sv += __shfl_xor(sv, m);
      if (tid == 0) ps[w] = sv;
    }
    __syncthreads();
    // r partial over 32 paired rows
    float r2 = 0.f;
#pragma unroll
    for (int r2i = 0; r2i < 32; ++r2i) {
      const unsigned hv = hP[(r2i << 8) + tid];
      r2 += pL[2 * r2i] * bf2f((unsigned short)hv) +
            pL[2 * r2i + 1] * bf2f((unsigned short)(hv >> 16));
    }
    pr[(w << 8) + tid] = r2;
    __syncthreads();  // barrier drains vmcnt: all partial stores done
    if (tid == 0)
      __hip_atomic_store(flagP + w * 32, (unsigned)(t + 1), __ATOMIC_RELEASE,
                         __HIP_MEMORY_SCOPE_AGENT);
  }

  // ==== epilogue: q_star = [q_final, r_final] (WG 0 only) ====
  if (w == 0) {
    wait_flags(flagP, (unsigned)NSTEPS, tid, dead);
    {
      const float* prv = pr + (wv4 * 16) * 256 + (l << 2);
      float rx = 0.f, ry = 0.f, rz = 0.f, rw = 0.f;
#pragma unroll
      for (int i = 0; i < 16; ++i) {
        const float4 v = *(const float4*)(prv + i * 256);
        rx += v.x; ry += v.y; rz += v.z; rw += v.w;
      }
      float* d = prL + wv4 * 256 + (l << 2);
      d[0] = rx; d[1] = ry; d[2] = rz; d[3] = rw;
      if (wv4 == 0) {
        float s = ps[l];
#pragma unroll
        for (int m = 32; m; m >>= 1) s += __shfl_xor(s, m);
        if (l == 0) sL[0] = fmaxf(s, 1e-35f);
      }
    }
    __syncthreads();
    float rsum = prL[tid] + prL[256 + tid] + prL[512 + tid] + prL[768 + tid];
    out[tid] = qrL[tid];
    out[256 + tid] = rsum / sL[0];
  }
}

extern "C" void kernel_launch(void* const* d_in, const int* in_sizes, int n_in,
                              void* d_out, int out_size, void* d_ws, size_t ws_size,
                              hipStream_t stream) {
  const float* h = (const float*)d_in[0];
  const float* W_ih = (const float*)d_in[1];
  const float* W_hh = (const float*)d_in[2];
  const float* b_ih = (const float*)d_in[3];
  const float* b_hh = (const float*)d_in[4];
  const float* W_a = (const float*)d_in[5];
  const float* b_a = (const float*)d_in[6];
  char* ws = (char*)d_ws;
  float* out = (float*)d_out;

  (void)hipFuncSetAttribute(reinterpret_cast<const void*>(s2s_main),
                            hipFuncAttributeMaxDynamicSharedMemorySize, SMEM_BYTES);

  k0_init<<<1, TT, 0, stream>>>(ws);
  k1_hp<<<256, 256, 0, stream>>>(h, W_a, b_a, ws);
  k2_pack<<<1024, 256, 0, stream>>>(h, W_ih, W_hh, b_ih, b_hh, ws);
  s2s_main<<<NWG, TT, SMEM_BYTES, stream>>>(ws, out);
}

// Round 5
// 26309.610 us; speedup vs baseline: 2.2006x; 1.9801x over previous
//
#include <hip/hip_runtime.h>
#include <stdint.h>

#define NN 4096      // nodes / steps
#define DD 256       // hidden dim
#define NWG 64       // workgroups
#define TT 256       // threads per WG
#define ROWS 64      // NN/NWG rows per WG
#define GR 16        // gate rows per WG (1024/NWG)
#define NSTEPS 4096
#define GUARD (1u << 20)

typedef float f32x4 __attribute__((ext_vector_type(4)));

// ---------------- workspace layout (bytes) ----------------
#define OFF_HDR      0u          // 64 x 64B: {u32 tag, f32 ps, pad...}
#define OFF_QS       4096u       // 64 x 128B: lineA {tag,q0,q1,q2} @+0, lineB {tag,q3,-,-} @+64
#define OFF_SCAL     12288u      // [0]=maxHpNorm bits, [1]=ebBound bits
#define OFF_PR       12352u      // 64*256 f32 partial r-tilde
#define OFF_EB       77888u      // 4096 f32  (h @ b_a)
#define OFF_BPACK    94272u      // 1024 f32 packed bias
#define OFF_WPACK    98368u      // 1024*512 f32 packed gate weights (+2097152)
#define OFF_HPB      2195520u    // 4096*256 bf16 packed [wg][k4][row] (Hp) (+2097152)
#define OFF_HP2      4292672u    // paired-row h bf16: [wg][r2:32][col:256] uint (+2097152)
// total 6,389,824 B

// ---------------- LDS layout ----------------
#define S_HPL    0u        // 32768  uint2 [k4:64][row:64]
#define S_HP     32768u    // 32768  uint  [r2:32][col:256]
#define S_WL     65536u    // 32768  f32   [16][512]
#define S_QRL    98304u    // 2048   f32   [512] : q | r
#define S_PRL    100352u   // 4096   f32   [4][256]
#define S_EL     104448u   // 1024   f32   [4][64]
#define S_PL     105472u   // 256    f32   [64]
#define S_GL     105728u   // 64     f32   [16]
#define S_CLS    105792u   // 16     f32   [4]
#define S_RED4   105808u   // 16
#define S_SL     105824u   // 16
#define S_EBL    105840u   // 256    f32   [64]
#define S_Q4     106096u   // 16     f32   [4]
#define SMEM_BYTES 106496

__device__ __forceinline__ float bf2f(unsigned short u) {
  return __uint_as_float(((unsigned)u) << 16);
}
__device__ __forceinline__ unsigned short f2bf(float f) {
  unsigned x = __float_as_uint(f);
  unsigned r = x + 0x7fffu + ((x >> 16) & 1u);
  return (unsigned short)(r >> 16);
}

// ---- coherent-bypass memory ops (sc0 sc1: skip L1/L2, device-coherent) ----
__device__ __forceinline__ f32x4 ld_v4(const void* p) {
  f32x4 v;
  asm volatile("global_load_dwordx4 %0, %1, off sc0 sc1\n\ts_waitcnt vmcnt(0)"
               : "=v"(v) : "v"(p) : "memory");
  return v;
}
__device__ __forceinline__ f32x4 ld_v4_async(const void* p) {
  f32x4 v;
  asm volatile("global_load_dwordx4 %0, %1, off sc0 sc1" : "=v"(v) : "v"(p) : "memory");
  return v;
}
__device__ __forceinline__ void st_v4(void* p, f32x4 v) {
  asm volatile("global_store_dwordx4 %0, %1, off sc0 sc1" :: "v"(p), "v"(v) : "memory");
}
__device__ __forceinline__ void st_f32(void* p, float v) {
  asm volatile("global_store_dword %0, %1, off sc0 sc1" :: "v"(p), "v"(v) : "memory");
}
__device__ __forceinline__ void vmdrain() {
  asm volatile("s_waitcnt vmcnt(0)" ::: "memory");
}

// ---------------- K0: init dynamic state ----------------
__global__ void k0_init(char* ws) {
  int t = threadIdx.x;
  unsigned* u = (unsigned*)ws;
  float* f = (float*)ws;
  for (int i = t; i < 64; i += TT) {
    u[(OFF_HDR >> 2) + i * 16] = 0u;
    f[(OFF_HDR >> 2) + i * 16 + 1] = 1.0f / NWG;
  }
  for (int i = t; i < 64; i += TT) {
    u[(OFF_QS >> 2) + i * 32] = 0u;
    u[(OFF_QS >> 2) + i * 32 + 16] = 0u;
  }
  if (t == 0) { u[OFF_SCAL / 4] = 0u; u[OFF_SCAL / 4 + 1] = 0u; }
  for (int i = t; i < 64 * 256; i += TT) f[(OFF_PR >> 2) + i] = 0.f;
}

// ---------------- K1: Hp = h @ W_a (bf16, packed), eb = h @ b_a, bounds ----------------
__global__ __launch_bounds__(256) void k1_hp(const float* __restrict__ h,
                                             const float* __restrict__ W_a,
                                             const float* __restrict__ b_a,
                                             char* ws) {
  __shared__ float hL1[16][256];
  __shared__ float scr[16][256];
  __shared__ float redN[4][16];
  __shared__ float redE[4][16];
  const int t = threadIdx.x, b = blockIdx.x;
  const int i0 = b * 16;
  for (int i = t; i < 16 * 256; i += 256) hL1[i >> 8][i & 255] = h[i0 * 256 + i];
  __syncthreads();
  float acc[16];
#pragma unroll
  for (int ii = 0; ii < 16; ++ii) acc[ii] = 0.f;
  for (int j = 0; j < 256; ++j) {
    float wa = W_a[j * 256 + t];
#pragma unroll
    for (int ii = 0; ii < 16; ++ii) acc[ii] += hL1[ii][j] * wa;
  }
#pragma unroll
  for (int ii = 0; ii < 16; ++ii) scr[ii][t] = acc[ii];
  const int lane = t & 63, wv = t >> 6;
  const float ba = b_a[t];
  for (int ii = 0; ii < 16; ++ii) {
    float a2 = acc[ii] * acc[ii];
    float eb = hL1[ii][t] * ba;
    for (int m = 32; m; m >>= 1) { a2 += __shfl_xor(a2, m); eb += __shfl_xor(eb, m); }
    if (lane == 0) { redN[wv][ii] = a2; redE[wv][ii] = eb; }
  }
  __syncthreads();
  unsigned* scal = (unsigned*)(ws + OFF_SCAL);
  float* ebg = (float*)(ws + OFF_EB);
  if (t < 16) {
    float n2 = redN[0][t] + redN[1][t] + redN[2][t] + redN[3][t];
    float ebv = redE[0][t] + redE[1][t] + redE[2][t] + redE[3][t];
    ebg[i0 + t] = ebv;
    atomicMax(scal + 0, __float_as_uint(sqrtf(n2)));
    atomicMax(scal + 1, __float_as_uint(fabsf(ebv)));
  }
  uint2* hpB = (uint2*)(ws + OFF_HPB);
  const int wq = b >> 2, sub = b & 3;
  for (int idx = t; idx < 16 * 64; idx += 256) {
    int ii = idx >> 6, k4 = idx & 63;
    unsigned short u0 = f2bf(scr[ii][4 * k4 + 0]);
    unsigned short u1 = f2bf(scr[ii][4 * k4 + 1]);
    unsigned short u2 = f2bf(scr[ii][4 * k4 + 2]);
    unsigned short u3 = f2bf(scr[ii][4 * k4 + 3]);
    uint2 pv;
    pv.x = (unsigned)u0 | ((unsigned)u1 << 16);
    pv.y = (unsigned)u2 | ((unsigned)u3 << 16);
    int rl = sub * 16 + ii;
    hpB[wq * 4096 + k4 * 64 + rl] = pv;
  }
}

// ---------------- K2: pack paired h (bf16), fold gate weights/bias ----------------
__global__ void k2_pack(const float* __restrict__ h, const float* __restrict__ W_ih,
                        const float* __restrict__ W_hh, const float* __restrict__ b_ih,
                        const float* __restrict__ b_hh, char* ws) {
  unsigned* hp2 = (unsigned*)(ws + OFF_HP2);
  float* wpack = (float*)(ws + OFF_WPACK);
  float* bpack = (float*)(ws + OFF_BPACK);
  int idx0 = blockIdx.x * blockDim.x + threadIdx.x;
  int stride = gridDim.x * blockDim.x;
  for (int i = idx0; i < NN * DD / 2; i += stride) {
    int col = i & 255;
    int r2 = (i >> 8) & 31;
    int w = i >> 13;
    int row0 = (w * 64 + 2 * r2) * 256 + col;
    hp2[i] = (unsigned)f2bf(h[row0]) | ((unsigned)f2bf(h[row0 + 256]) << 16);
  }
  for (int i = idx0; i < 1024 * 512; i += stride) {
    int row = i >> 9, c = i & 511;
    int g = row >> 8, d = row & 255;
    int wq = d >> 2, dl = d & 3;
    float v = W_ih[row * 512 + c];
    if (c < 256) v += W_hh[row * 256 + c];
    wpack[(wq * GR + g * 4 + dl) * 512 + c] = v;
  }
  for (int i = idx0; i < 1024; i += stride) {
    int g = i >> 8, d = i & 255, wq = d >> 2, dl = d & 3;
    bpack[wq * GR + g * 4 + dl] = b_ih[i] + b_hh[i];
  }
}

// ---------------- main persistent kernel ----------------
__global__ __launch_bounds__(TT, 1) void s2s_main(char* __restrict__ ws,
                                                  float* __restrict__ out) {
  extern __shared__ char smem[];
  uint2* HpL = (uint2*)(smem + S_HPL);
  unsigned* hP = (unsigned*)(smem + S_HP);
  float* wL = (float*)(smem + S_WL);
  float* qrL = (float*)(smem + S_QRL);
  float* prL = (float*)(smem + S_PRL);
  float* eL = (float*)(smem + S_EL);
  float* pL = (float*)(smem + S_PL);
  float* gL = (float*)(smem + S_GL);
  float* cLs = (float*)(smem + S_CLS);
  float* red4 = (float*)(smem + S_RED4);
  float* sL = (float*)(smem + S_SL);
  float* ebL = (float*)(smem + S_EBL);
  float* qL4 = (float*)(smem + S_Q4);

  const int w = blockIdx.x, tid = threadIdx.x;
  char* hdrBase = ws + OFF_HDR;
  char* qsBase = ws + OFF_QS;
  const unsigned* scal = (const unsigned*)(ws + OFF_SCAL);
  float* pr = (float*)(ws + OFF_PR);
  const float* ebg = (const float*)(ws + OFF_EB);
  const float* bpack = (const float*)(ws + OFF_BPACK);
  const float* wpack = (const float*)(ws + OFF_WPACK);
  const uint2* hpB = (const uint2*)(ws + OFF_HPB) + (size_t)w * 4096;
  const unsigned* hp2 = (const unsigned*)(ws + OFF_HP2) + (size_t)w * 8192;

  for (int i = tid; i < 4096; i += TT) HpL[i] = hpB[i];
  for (int i = tid; i < 8192; i += TT) hP[i] = hp2[i];
  for (int i = tid; i < 8192; i += TT) wL[i] = wpack[(size_t)w * 8192 + i];
  if (tid < 64) ebL[tid] = ebg[w * 64 + tid];
  if (tid < 4) cLs[tid] = 0.f;
  qrL[tid] = 0.f;
  qrL[256 + tid] = 0.f;
  const float maxHpN = __uint_as_float(scal[0]);
  const float ebB = __uint_as_float(scal[1]);
  __syncthreads();

  const int gr_lr = tid >> 4, gr_li = tid & 15;
  const float* wrow = wL + gr_lr * 512;
  const float brow = bpack[w * GR + gr_lr];
  const int wv4 = tid >> 6, l = tid & 63;
  float psW = 0.f;  // valid in tid 0 only

  for (int t = 0; t < NSTEPS; ++t) {
    // ==== phase A: q_t = LSTM(q_{t-1}, r_{t-1}) ====
    float acc = 0.f;
#pragma unroll
    for (int j = 0; j < 4; ++j) {
      int c0 = gr_li * 4 + j * 64;
      const float4 wv = *(const float4*)(wrow + c0);
      const float4 qv = *(const float4*)(qrL + c0);
      acc += wv.x * qv.x + wv.y * qv.y + wv.z * qv.z + wv.w * qv.w;
    }
    // wait partials headers (tag >= t), grab ps from same 16B line
    if (tid < 64) {
      const char* hp = hdrBase + tid * 64;
      float psv;
      unsigned guard = 0;
      for (;;) {
        f32x4 hv = ld_v4(hp);
        if (__float_as_uint(hv.x) >= (unsigned)t || ++guard > GUARD) { psv = hv.y; break; }
      }
      float s = psv;
#pragma unroll
      for (int m = 32; m; m >>= 1) s += __shfl_xor(s, m);
      if (tid == 0) sL[0] = fmaxf(s, 1e-35f);
    }
    __syncthreads();
    // combine partial r: wave wv4 sums 16 slices, lane l -> 4 cols (rotated by w)
    {
      f32x4 tv[16];
#pragma unroll
      for (int i = 0; i < 16; ++i) {
        int v = (wv4 * 16 + i + w) & 63;
        tv[i] = ld_v4_async(pr + v * 256 + (l << 2));
      }
      vmdrain();
      __builtin_amdgcn_sched_barrier(0);
      float rx = 0.f, ry = 0.f, rz = 0.f, rw = 0.f;
#pragma unroll
      for (int i = 0; i < 16; ++i) { rx += tv[i].x; ry += tv[i].y; rz += tv[i].z; rw += tv[i].w; }
      float* d = prL + wv4 * 256 + (l << 2);
      d[0] = rx; d[1] = ry; d[2] = rz; d[3] = rw;
    }
    __syncthreads();
    {
      float rsum = prL[tid] + prL[256 + tid] + prL[512 + tid] + prL[768 + tid];
      qrL[256 + tid] = rsum / sL[0];  // r_{t-1}
    }
    __syncthreads();
    // Wr @ r
#pragma unroll
    for (int j = 4; j < 8; ++j) {
      int c0 = gr_li * 4 + j * 64;
      const float4 wv = *(const float4*)(wrow + c0);
      const float4 qv = *(const float4*)(qrL + c0);
      acc += wv.x * qv.x + wv.y * qv.y + wv.z * qv.z + wv.w * qv.w;
    }
    acc += __shfl_xor(acc, 8);
    acc += __shfl_xor(acc, 4);
    acc += __shfl_xor(acc, 2);
    acc += __shfl_xor(acc, 1);
    if (gr_li == 0) gL[gr_lr] = acc + brow;
    __syncthreads();
    if (tid < 4) {
      float gi = gL[tid], gf = gL[4 + tid], gg = gL[8 + tid], go = gL[12 + tid];
      float co = cLs[tid];
      float si = 1.f / (1.f + __expf(-gi));
      float sf = 1.f / (1.f + __expf(-gf));
      float so = 1.f / (1.f + __expf(-go));
      float cn = sf * co + si * tanhf(gg);
      cLs[tid] = cn;
      qL4[tid] = so * tanhf(cn);
    }
    __syncthreads();
    if (tid == 0) {
      float4 qv4 = *(const float4*)qL4;
      f32x4 lineA, lineB;
      lineA.x = __uint_as_float((unsigned)(t + 1));
      lineA.y = qv4.x; lineA.z = qv4.y; lineA.w = qv4.z;
      lineB.x = __uint_as_float((unsigned)(t + 1));
      lineB.y = qv4.w; lineB.z = 0.f; lineB.w = 0.f;
      st_v4(qsBase + w * 128, lineA);       // self-validating: no drain needed
      st_v4(qsBase + w * 128 + 64, lineB);
    }

    // ==== phase B: e = Hp q + eb, partials ====
    if (tid < 64) {
      const char* qp = qsBase + tid * 128;
      f32x4 a, b;
      unsigned guard = 0;
      for (;;) {
        a = ld_v4_async(qp);
        b = ld_v4_async(qp + 64);
        vmdrain();
        __builtin_amdgcn_sched_barrier(0);
        unsigned need = (unsigned)(t + 1);
        if ((__float_as_uint(a.x) >= need && __float_as_uint(b.x) >= need) ||
            ++guard > GUARD) break;
      }
      float* qd = qrL + tid * 4;
      qd[0] = a.y; qd[1] = a.z; qd[2] = a.w; qd[3] = b.y;
    }
    __syncthreads();
    float qv = qrL[tid];
    float nr = qv * qv;
#pragma unroll
    for (int m = 32; m; m >>= 1) nr += __shfl_xor(nr, m);
    if (l == 0) red4[wv4] = nr;
    __syncthreads();
    const float qnorm = sqrtf(red4[0] + red4[1] + red4[2] + red4[3]);
    const float Mhat = 0.5f * maxHpN * qnorm + ebB;
    // e partial: wave wv4 covers k4 in [wv4*16,+16), lane l = row
    float eacc = 0.f;
#pragma unroll
    for (int j = 0; j < 16; ++j) {
      const int k4 = wv4 * 16 + j;
      const uint2 hp = HpL[(k4 << 6) + l];
      const float* qp = qrL + (k4 << 2);
      eacc += bf2f((unsigned short)(hp.x)) * qp[0] +
              bf2f((unsigned short)(hp.x >> 16)) * qp[1] +
              bf2f((unsigned short)(hp.y)) * qp[2] +
              bf2f((unsigned short)(hp.y >> 16)) * qp[3];
    }
    eL[(wv4 << 6) + l] = eacc;
    __syncthreads();
    if (tid < 64) {
      float e = eL[tid] + eL[64 + tid] + eL[128 + tid] + eL[192 + tid] + ebL[tid];
      float p = __expf(fminf(e - Mhat, 60.f));
      pL[tid] = p;
      float sv = p;
#pragma unroll
      for (int m = 32; m; m >>= 1) sv += __shfl_xor(sv, m);
      if (tid == 0) psW = sv;
    }
    __syncthreads();
    // r partial over 32 paired rows
    float r2 = 0.f;
#pragma unroll
    for (int r2i = 0; r2i < 32; ++r2i) {
      const unsigned hv = hP[(r2i << 8) + tid];
      r2 += pL[2 * r2i] * bf2f((unsigned short)hv) +
            pL[2 * r2i + 1] * bf2f((unsigned short)(hv >> 16));
    }
    st_f32(pr + (w << 8) + tid, r2);
    vmdrain();        // each wave drains its own partial stores
    __syncthreads();  // => all 4 waves' stores complete
    if (tid == 0) {
      f32x4 hv4;
      hv4.x = __uint_as_float((unsigned)(t + 1));
      hv4.y = psW; hv4.z = 0.f; hv4.w = 0.f;
      st_v4(hdrBase + w * 64, hv4);
    }
  }

  // ==== epilogue: q_star = [q_final, r_final] (WG 0 only) ====
  if (w == 0) {
    if (tid < 64) {
      const char* hp = hdrBase + tid * 64;
      float psv;
      unsigned guard = 0;
      for (;;) {
        f32x4 hv = ld_v4(hp);
        if (__float_as_uint(hv.x) >= (unsigned)NSTEPS || ++guard > GUARD) { psv = hv.y; break; }
      }
      float s = psv;
#pragma unroll
      for (int m = 32; m; m >>= 1) s += __shfl_xor(s, m);
      if (tid == 0) sL[0] = fmaxf(s, 1e-35f);
    }
    __syncthreads();
    {
      f32x4 tv[16];
#pragma unroll
      for (int i = 0; i < 16; ++i) {
        int v = (wv4 * 16 + i) & 63;
        tv[i] = ld_v4_async(pr + v * 256 + (l << 2));
      }
      vmdrain();
      __builtin_amdgcn_sched_barrier(0);
      float rx = 0.f, ry = 0.f, rz = 0.f, rw = 0.f;
#pragma unroll
      for (int i = 0; i < 16; ++i) { rx += tv[i].x; ry += tv[i].y; rz += tv[i].z; rw += tv[i].w; }
      float* d = prL + wv4 * 256 + (l << 2);
      d[0] = rx; d[1] = ry; d[2] = rz; d[3] = rw;
    }
    __syncthreads();
    float rsum = prL[tid] + prL[256 + tid] + prL[512 + tid] + prL[768 + tid];
    out[tid] = qrL[tid];
    out[256 + tid] = rsum / sL[0];
  }
}

extern "C" void kernel_launch(void* const* d_in, const int* in_sizes, int n_in,
                              void* d_out, int out_size, void* d_ws, size_t ws_size,
                              hipStream_t stream) {
  const float* h = (const float*)d_in[0];
  const float* W_ih = (const float*)d_in[1];
  const float* W_hh = (const float*)d_in[2];
  const float* b_ih = (const float*)d_in[3];
  const float* b_hh = (const float*)d_in[4];
  const float* W_a = (const float*)d_in[5];
  const float* b_a = (const float*)d_in[6];
  char* ws = (char*)d_ws;
  float* out = (float*)d_out;

  (void)hipFuncSetAttribute(reinterpret_cast<const void*>(s2s_main),
                            hipFuncAttributeMaxDynamicSharedMemorySize, SMEM_BYTES);

  k0_init<<<1, TT, 0, stream>>>(ws);
  k1_hp<<<256, 256, 0, stream>>>(h, W_a, b_a, ws);
  k2_pack<<<1024, 256, 0, stream>>>(h, W_ih, W_hh, b_ih, b_hh, ws);
  s2s_main<<<NWG, TT, SMEM_BYTES, stream>>>(ws, out);
}